// Round 7
// baseline (195.610 us; speedup 1.0000x reference)
//
#include <hip/hip_runtime.h>
#include <hip/hip_fp16.h>

typedef float    f32x4 __attribute__((ext_vector_type(4)));
typedef _Float16 f16x2 __attribute__((ext_vector_type(2)));
typedef _Float16 f16x4 __attribute__((ext_vector_type(4)));
typedef _Float16 f16x8 __attribute__((ext_vector_type(8)));

#define BS 8
#define NN 2048
#define DK 128
#define DM 64
#define MIXOFF (1024 * DK)  // halfs between mix-0 and mix-1 rows of one batch
// log2(e) / sqrt(128): folds softmax temperature AND exp->exp2 conversion into Q
#define QSCALE 0.12751744116926208f

#define MFMA32(a, b, c) __builtin_amdgcn_mfma_f32_16x16x32_f16((a), (b), (c), 0, 0, 0)
#define EXP2(x) __builtin_amdgcn_exp2f(x)

__device__ __forceinline__ f16x2 pkrtz(float x, float y) {
  return __builtin_bit_cast(f16x2, __builtin_amdgcn_cvt_pkrtz(x, y));
}

// async global->LDS DMA, 16B per lane; no VGPR transit (allocator-proof)
__device__ __forceinline__ void load_lds16(const _Float16* g, _Float16* l) {
  __builtin_amdgcn_global_load_lds(
      (const __attribute__((address_space(1))) void*)(uintptr_t)g,
      (__attribute__((address_space(3))) void*)(uint32_t)(uintptr_t)l, 16, 0, 0);
}

// ---- fused prep: K f32->f16 (512 blk), V transpose 64x64 (512 blk), q-mean (64 blk) ----
__global__ void prep_k(const float* __restrict__ kt, _Float16* __restrict__ kh,
                       const float* __restrict__ vt, _Float16* __restrict__ vT,
                       const float* __restrict__ qt, float* __restrict__ qpart) {
  __shared__ float tile[64][65];
  __shared__ float red[256];
  int blk = blockIdx.x;
  int t = threadIdx.x;
  if (blk < 512) {
    size_t base = (size_t)blk * 4096;
#pragma unroll
    for (int j = 0; j < 4; ++j) {
      size_t i = base + j * 1024 + t * 4;
      f32x4 v = *(const f32x4*)(kt + i);
      f16x4 h;
      h[0] = (_Float16)v[0]; h[1] = (_Float16)v[1];
      h[2] = (_Float16)v[2]; h[3] = (_Float16)v[3];
      *(f16x4*)(kh + i) = h;
    }
  } else if (blk < 1024) {
    int i2 = blk - 512;
    int b = i2 >> 6;
    int rem = i2 & 63;
    int j0 = (rem & 31) * 64;   // key tile
    int c0 = (rem >> 5) * 64;   // channel tile
    int tx = t & 63, ty = t >> 6;
    const float* src = vt + ((size_t)b * NN + j0) * DK + c0;
#pragma unroll
    for (int rr = 0; rr < 16; ++rr) {
      int row = ty * 16 + rr;
      tile[row][tx] = src[(size_t)row * DK + tx];
    }
    __syncthreads();
    _Float16* dst = vT + ((size_t)b * DK + c0) * NN + j0;
    int chl = t >> 4;
    int k4 = (t & 15) * 4;
#pragma unroll
    for (int r2 = 0; r2 < 4; ++r2) {
      int ch = r2 * 16 + chl;
      f16x4 h;
      h[0] = (_Float16)tile[k4 + 0][ch]; h[1] = (_Float16)tile[k4 + 1][ch];
      h[2] = (_Float16)tile[k4 + 2][ch]; h[3] = (_Float16)tile[k4 + 3][ch];
      *(f16x4*)(dst + (size_t)ch * NN + k4) = h;
    }
  } else {
    int i = blk - 1024;
    int b = i >> 3, seg = i & 7;
    int c = t & 127, h = t >> 7;
    const float* p = qt + ((size_t)b * NN + seg * 256 + h * 128) * DK + c;
    float s = 0.f;
#pragma unroll 8
    for (int n = 0; n < 128; ++n) s += p[(size_t)n * DK];
    red[t] = s;
    __syncthreads();
    if (t < 128) qpart[(size_t)i * 128 + t] = red[t] + red[t + 128];
  }
}

// Stage step S (32 keys): K 2m x 32k x 64ch = 8KB + V 32k x 128ch = 8KB into
// buffer BUF. 1024 16B units, 256 threads x 4 (2 K + 2 V). Same per-unit maps
// as R12/R17 (verified), re-indexed: K unit (m, rK=t>>3, uuK swz), V unit
// (ch, kslot=t&3, uuV swz). V dst t*8 == ch*32 + kslot*8 identity; uuV is
// invariant under ch->ch+64 (delta 80 == 0 mod 4); swz(perm)==swz(perm+4)==gK.
#define STAGE(BUF, S) do {                                                  \
    _Float16* db_ = stg + (BUF) * 8192;                                     \
    load_lds16(khg + gKst + (S) * 2048,          db_ + t * 8);              \
    load_lds16(khg + gKst + MIXOFF + (S) * 2048, db_ + 2048 + t * 8);       \
    load_lds16(vTg + gVst + (S) * 32,            db_ + 4096 + t * 8);       \
    load_lds16(vTg + gVst + 64 * NN + (S) * 32,  db_ + 6144 + t * 8);       \
  } while (0)

// ---------------- main: mixture flash attention, phase-decoupled blocks -------
// R18: the 43-51us plateau across ALL lockstep configs (R0/R12/R13/R14/R17) is
// explained by ZERO inter-pipe overlap: per-CU pipe floors (MFMA 13.6us + LDS
// 11us + trans 7.4us + VALU 4.7us + DMA ~8-15us) SUM to the observed 44-52us;
// a single barrier keeps every wave in the same phase so the pipes run
// sequentially. Fix: 4 independent blocks/CU with their own barriers -> phases
// drift, block A's MFMA overlaps block B's DMA/exp2. Grid 1024 = b(8) x
// qb(32: 64q) x kb(4: 512 keys); 256 thr = 4 waves (m,u), 32q/wave (2 su) so
// the ratio-2 MFMA:ds_read structure (per-CU LDS traffic 3MB) is preserved.
// 16 steps x 32 keys, 16KB/step, 32KB dbuf x 4 blocks = 128KB LDS/CU. Split-K
// partials to global + merge_k (R17 scheme, kb=4). Staging/read maps verbatim
// R12-verified, re-indexed for the 32-key step.
__global__ __launch_bounds__(256, 4) void attn_k(const float* __restrict__ qt,
                                                 const _Float16* __restrict__ khg,
                                                 const _Float16* __restrict__ vTg,
                                                 float* __restrict__ opart,
                                                 float* __restrict__ lpart) {
  __shared__ __align__(16) char smem[32768];
  _Float16* stg = (_Float16*)smem;  // [2][8192] halfs = 2 x 16KB staging
  const int b = blockIdx.x & 7;
  const int qb = (blockIdx.x >> 3) & 31;  // 64-q tile
  const int kb = blockIdx.x >> 8;         // 512-key quarter
  const int t = threadIdx.x;
  const int wv = t >> 6;
  const int m = wv >> 1;        // mixture
  const int u = wv & 1;         // 32-query tile within the 64
  const int lane = t & 63;
  const int quad = lane >> 4, l16 = lane & 15;
  const int perm = ((l16 >> 2) << 3) | (l16 & 3);
  const int bq = b * (NN * DK);
  const int bV = b * (DK * NN);

  // Q fragments: 2 subtiles x 2 chunks, f32 load + scale + pack in-register
  f16x8 qf[2][2];  // [su][chunk]
#pragma unroll
  for (int su = 0; su < 2; ++su)
#pragma unroll
    for (int c = 0; c < 2; ++c) {
      const float* qp_ = qt + bq + m * MIXOFF +
                         (qb * 64 + u * 32 + su * 16 + l16) * DM + quad * 8 + c * 32;
      f32x4 v0 = *(const f32x4*)qp_;
      f32x4 v1 = *(const f32x4*)(qp_ + 4);
      union { f16x8 v; f16x2 h[4]; } w;
      w.h[0] = pkrtz(v0[0] * QSCALE, v0[1] * QSCALE);
      w.h[1] = pkrtz(v0[2] * QSCALE, v0[3] * QSCALE);
      w.h[2] = pkrtz(v1[0] * QSCALE, v1[1] * QSCALE);
      w.h[3] = pkrtz(v1[2] * QSCALE, v1[3] * QSCALE);
      qf[su][c] = w.v;
    }

  // staging offsets (halfs): R12 unit maps, 256 units per K m-region / 512 V
  const int rK = t >> 3;                                            // key 0..31
  const int uuK = (t & 7) ^ ((rK & 3) ^ (((rK >> 3) & 1) << 2));    // R12 swizzle
  const int chV = t >> 2;                                           // ch 0..63
  const int uuV = (t & 3) ^ ((chV + (chV >> 2)) & 3);
  const int gKst = bq + kb * 32768 + rK * 64 + uuK * 8;
  const int gVst = bV + chV * NN + kb * 512 + uuV * 8;

  // LDS read offsets (halfs); R12 conflict-free maps
  const int gK = (l16 & 3) ^ (((l16 >> 2) & 1) << 2);
  const int hV = (l16 + (l16 >> 2)) & 3;
  const int kA = (quad ^ gK) * 8;
  const int kB = ((quad + 4) ^ gK) * 8;
  const int kbase = m * 2048 + perm * 64;
  const int vboff = 4096 + l16 * 32 + (quad ^ hV) * 8;

  const f32x4 z = {0.f, 0.f, 0.f, 0.f};
  f32x4 acc[2][8];  // [su][cc]
  float lsum[2] = {0.f, 0.f};
#pragma unroll
  for (int su = 0; su < 2; ++su)
#pragma unroll
    for (int cc = 0; cc < 8; ++cc) acc[su][cc] = z;

  STAGE(0, 0);
  int buf = 0;
  for (int s = 0; s < 16; ++s) {
    __syncthreads();  // tile for step s landed; reads of buf^1 done
    if (s + 1 < 16) STAGE(buf ^ 1, s + 1);
    const _Float16* sb_ = stg + buf * 8192;
    const _Float16* kp_ = sb_ + kbase;
    f16x8 kf0 = *(const f16x8*)(kp_ + kA);
    f16x8 kf1 = *(const f16x8*)(kp_ + kB);
    f16x8 kf2 = *(const f16x8*)(kp_ + 256 + kA);
    f16x8 kf3 = *(const f16x8*)(kp_ + 256 + kB);
    f16x8 pw[2];
#pragma unroll
    for (int su = 0; su < 2; ++su) {
      f32x4 s0 = MFMA32(kf1, qf[su][1], MFMA32(kf0, qf[su][0], z));
      f32x4 s1 = MFMA32(kf3, qf[su][1], MFMA32(kf2, qf[su][0], z));
      float e0 = EXP2(s0[0]), e1 = EXP2(s0[1]), e2 = EXP2(s0[2]), e3 = EXP2(s0[3]);
      float e4 = EXP2(s1[0]), e5 = EXP2(s1[1]), e6 = EXP2(s1[2]), e7 = EXP2(s1[3]);
      lsum[su] += ((e0 + e1) + (e2 + e3)) + ((e4 + e5) + (e6 + e7));
      union { f16x8 v; f16x2 h[4]; } w;
      w.h[0] = pkrtz(e0, e1); w.h[1] = pkrtz(e2, e3);
      w.h[2] = pkrtz(e4, e5); w.h[3] = pkrtz(e6, e7);
      pw[su] = w.v;
    }
    const _Float16* vb_ = sb_ + vboff;
    f16x8 vf[8];
#pragma unroll
    for (int cc = 0; cc < 8; ++cc) vf[cc] = *(const f16x8*)(vb_ + cc * 512);
#pragma unroll
    for (int cc = 0; cc < 8; ++cc)
#pragma unroll
      for (int su = 0; su < 2; ++su) acc[su][cc] = MFMA32(vf[cc], pw[su], acc[su][cc]);
    buf ^= 1;
  }

  // ---- epilogue: pure global stores of split-K partials (no LDS phases) ----
#pragma unroll
  for (int su = 0; su < 2; ++su) {
    lsum[su] += __shfl_xor(lsum[su], 16);
    lsum[su] += __shfl_xor(lsum[su], 32);
  }
  const size_t plane = (size_t)((b * 4 + kb) * 2 + m);
#pragma unroll
  for (int su = 0; su < 2; ++su) {
    const int qg = qb * 64 + u * 32 + su * 16 + l16;
    if (quad == 0) lpart[plane * 2048 + qg] = lsum[su];
    float* op = opart + (plane * 2048 + qg) * (size_t)128 + quad * 4;
#pragma unroll
    for (int cc = 0; cc < 8; ++cc) *(f32x4*)(op + cc * 16) = acc[su][cc];
  }
}

// ---- merge: prior softmax (verbatim logic) + cross-block split-K combine ----
// out[b][q][d] = sum_m prp[b*2+m] * (sum_kb Op[b,kb,m,q,d]) / (sum_kb lp[b,kb,m,q])
__global__ __launch_bounds__(256) void merge_k(const float* __restrict__ qpart,
                                               const float* __restrict__ kern,
                                               const float* __restrict__ opart,
                                               const float* __restrict__ lpart,
                                               float* __restrict__ out) {
  __shared__ float barL[1024];
  __shared__ float lgp[16], exq[16], prp[16];
  const int t = threadIdx.x;
  const int b = blockIdx.x & 7;
  const int qc = blockIdx.x >> 3;  // 0..31, 64 q rows each
  for (int e = t; e < 1024; e += 256) {
    int bb = e >> 7, c = e & 127;
    float ss = 0.f;
#pragma unroll
    for (int seg = 0; seg < 8; ++seg) ss += qpart[(size_t)(bb * 8 + seg) * 128 + c];
    barL[e] = ss * (1.0f / 2048.0f);
  }
  __syncthreads();
  if (t < 16) {
    int mm = t >> 3, bb = t & 7;
    float ss = 0.f;
    for (int c = 0; c < DK; ++c) ss += kern[mm * DK + c] * barL[bb * 128 + c];
    lgp[t] = ss;
  }
  __syncthreads();
  if (t < 16) {
    int mm = t >> 3;
    float mx = lgp[mm * 8];
    for (int i2 = 1; i2 < 8; ++i2) mx = fmaxf(mx, lgp[mm * 8 + i2]);
    exq[t] = __expf(lgp[t] - mx);
  }
  __syncthreads();
  if (t < 16) {
    int mm = t >> 3;
    float sm = 0.f;
    for (int i2 = 0; i2 < 8; ++i2) sm += exq[mm * 8 + i2];
    prp[t] = exq[t] / sm;  // flat[m*8+b]; read as [b*2+m] (TF reshape quirk)
  }
  __syncthreads();
  const float w0 = prp[b * 2 + 0], w1 = prp[b * 2 + 1];
  const int q = qc * 64 + (t >> 2);
  const int dc = (t & 3) * 32;
  float l0 = 0.f, l1 = 0.f;
#pragma unroll
  for (int kb = 0; kb < 4; ++kb) {
    l0 += lpart[((size_t)((b * 4 + kb) * 2 + 0)) * 2048 + q];
    l1 += lpart[((size_t)((b * 4 + kb) * 2 + 1)) * 2048 + q];
  }
  const float r0 = w0 / l0;
  const float r1 = w1 / l1;
  float* po = out + ((size_t)b * NN + q) * DK + dc;
#pragma unroll
  for (int g = 0; g < 8; ++g) {
    f32x4 o = {0.f, 0.f, 0.f, 0.f};
#pragma unroll
    for (int kb = 0; kb < 4; ++kb) {
      const float* p0 = opart + (((size_t)((b * 4 + kb) * 2 + 0)) * 2048 + q) * 128 + dc;
      const float* p1 = opart + (((size_t)((b * 4 + kb) * 2 + 1)) * 2048 + q) * 128 + dc;
      f32x4 a0 = *(const f32x4*)(p0 + g * 4);
      f32x4 a1 = *(const f32x4*)(p1 + g * 4);
#pragma unroll
      for (int e = 0; e < 4; ++e) o[e] += a0[e] * r0 + a1[e] * r1;
    }
    *(f32x4*)(po + g * 4) = o;
  }
}

extern "C" void kernel_launch(void* const* d_in, const int* in_sizes, int n_in,
                              void* d_out, int out_size, void* d_ws, size_t ws_size,
                              hipStream_t stream) {
  const float* qt = (const float*)d_in[0];
  const float* kt = (const float*)d_in[1];
  const float* vt = (const float*)d_in[2];
  const float* kern = (const float*)d_in[3];
  float* out = (float*)d_out;

  char* ws = (char*)d_ws;
  float* qpart = (float*)(ws + 4096);          // 64*128 floats (32 KB)
  _Float16* khp = (_Float16*)(ws + 65536);     // 2M halfs (4 MB)
  _Float16* vTp = khp + (size_t)BS * NN * DK;  // 2M halfs (4 MB)
  float* opart = (float*)(ws + (32u << 20));   // [8b][4kb][2m][2048q][128d] f32 (64 MB)
  float* lpart = (float*)(ws + (96u << 20));   // [8b][4kb][2m][2048q] f32 (512 KB)

  prep_k<<<dim3(1088), dim3(256), 0, stream>>>(kt, khp, vt, vTp, qt, qpart);
  attn_k<<<dim3(1024), dim3(256), 0, stream>>>(qt, khp, vTp, opart, lpart);
  merge_k<<<dim3(256), dim3(256), 0, stream>>>(qpart, kern, opart, lpart, out);
}

// Round 8
// 128.356 us; speedup vs baseline: 1.5240x; 1.5240x over previous
//
#include <hip/hip_runtime.h>
#include <hip/hip_fp16.h>

typedef float    f32x4 __attribute__((ext_vector_type(4)));
typedef _Float16 f16x2 __attribute__((ext_vector_type(2)));
typedef _Float16 f16x4 __attribute__((ext_vector_type(4)));
typedef _Float16 f16x8 __attribute__((ext_vector_type(8)));

#define BS 8
#define NN 2048
#define DK 128
#define DM 64
#define MIXOFF (1024 * DK)  // halfs between mix-0 and mix-1 rows of one batch
// log2(e) / sqrt(128): folds softmax temperature AND exp->exp2 conversion into Q
#define QSCALE 0.12751744116926208f

#define MFMA32(a, b, c) __builtin_amdgcn_mfma_f32_16x16x32_f16((a), (b), (c), 0, 0, 0)
#define EXP2(x) __builtin_amdgcn_exp2f(x)

__device__ __forceinline__ f16x2 pkrtz(float x, float y) {
  return __builtin_bit_cast(f16x2, __builtin_amdgcn_cvt_pkrtz(x, y));
}

// async global->LDS DMA, 16B per lane; no VGPR transit (allocator-proof)
__device__ __forceinline__ void load_lds16(const _Float16* g, _Float16* l) {
  __builtin_amdgcn_global_load_lds(
      (const __attribute__((address_space(1))) void*)(uintptr_t)g,
      (__attribute__((address_space(3))) void*)(uint32_t)(uintptr_t)l, 16, 0, 0);
}

// ---- fused prep: K f32->f16 (512 blk), V transpose 64x64 (512 blk), q-mean (64 blk) ----
__global__ void prep_k(const float* __restrict__ kt, _Float16* __restrict__ kh,
                       const float* __restrict__ vt, _Float16* __restrict__ vT,
                       const float* __restrict__ qt, float* __restrict__ qpart) {
  __shared__ float tile[64][65];
  __shared__ float red[256];
  int blk = blockIdx.x;
  int t = threadIdx.x;
  if (blk < 512) {
    size_t base = (size_t)blk * 4096;
#pragma unroll
    for (int j = 0; j < 4; ++j) {
      size_t i = base + j * 1024 + t * 4;
      f32x4 v = *(const f32x4*)(kt + i);
      f16x4 h;
      h[0] = (_Float16)v[0]; h[1] = (_Float16)v[1];
      h[2] = (_Float16)v[2]; h[3] = (_Float16)v[3];
      *(f16x4*)(kh + i) = h;
    }
  } else if (blk < 1024) {
    int i2 = blk - 512;
    int b = i2 >> 6;
    int rem = i2 & 63;
    int j0 = (rem & 31) * 64;   // key tile
    int c0 = (rem >> 5) * 64;   // channel tile
    int tx = t & 63, ty = t >> 6;
    const float* src = vt + ((size_t)b * NN + j0) * DK + c0;
#pragma unroll
    for (int rr = 0; rr < 16; ++rr) {
      int row = ty * 16 + rr;
      tile[row][tx] = src[(size_t)row * DK + tx];
    }
    __syncthreads();
    _Float16* dst = vT + ((size_t)b * DK + c0) * NN + j0;
    int chl = t >> 4;
    int k4 = (t & 15) * 4;
#pragma unroll
    for (int r2 = 0; r2 < 4; ++r2) {
      int ch = r2 * 16 + chl;
      f16x4 h;
      h[0] = (_Float16)tile[k4 + 0][ch]; h[1] = (_Float16)tile[k4 + 1][ch];
      h[2] = (_Float16)tile[k4 + 2][ch]; h[3] = (_Float16)tile[k4 + 3][ch];
      *(f16x4*)(dst + (size_t)ch * NN + k4) = h;
    }
  } else {
    int i = blk - 1024;
    int b = i >> 3, seg = i & 7;
    int c = t & 127, h = t >> 7;
    const float* p = qt + ((size_t)b * NN + seg * 256 + h * 128) * DK + c;
    float s = 0.f;
#pragma unroll 8
    for (int n = 0; n < 128; ++n) s += p[(size_t)n * DK];
    red[t] = s;
    __syncthreads();
    if (t < 128) qpart[(size_t)i * 128 + t] = red[t] + red[t + 128];
  }
}

// Stage step S (32 keys): K 2m x 32k x 64ch = 8KB + V 32k x 128ch = 8KB into
// buffer BUF. 1024 16B units, 256 threads x 4 (2 K + 2 V). Same per-unit maps
// as R12/R17 (verified), re-indexed: K unit (m, rK=t>>3, uuK swz), V unit
// (ch, kslot=t&3, uuV swz). V dst t*8 == ch*32 + kslot*8 identity; uuV is
// invariant under ch->ch+64 (delta 80 == 0 mod 4); swz(perm)==swz(perm+4)==gK.
#define STAGE(BUF, S) do {                                                  \
    _Float16* db_ = stg + (BUF) * 8192;                                     \
    load_lds16(khg + gKst + (S) * 2048,          db_ + t * 8);              \
    load_lds16(khg + gKst + MIXOFF + (S) * 2048, db_ + 2048 + t * 8);       \
    load_lds16(vTg + gVst + (S) * 32,            db_ + 4096 + t * 8);       \
    load_lds16(vTg + gVst + 64 * NN + (S) * 32,  db_ + 6144 + t * 8);       \
  } while (0)

// ---------------- main: mixture flash attention, phase-decoupled blocks -------
// R18 structure, UNCHANGED for R19 (this round only fixes merge_k so attn_k's
// counters become visible): grid 1024 = b(8) x qb(32: 64q) x kb(4: 512 keys);
// 256 thr = 4 waves (m,u); 16 steps x 32 keys, 16KB/step, 32KB dbuf x 4
// blocks/CU = 128KB LDS. Split-K partials to global + merge_k.
__global__ __launch_bounds__(256, 4) void attn_k(const float* __restrict__ qt,
                                                 const _Float16* __restrict__ khg,
                                                 const _Float16* __restrict__ vTg,
                                                 float* __restrict__ opart,
                                                 float* __restrict__ lpart) {
  __shared__ __align__(16) char smem[32768];
  _Float16* stg = (_Float16*)smem;  // [2][8192] halfs = 2 x 16KB staging
  const int b = blockIdx.x & 7;
  const int qb = (blockIdx.x >> 3) & 31;  // 64-q tile
  const int kb = blockIdx.x >> 8;         // 512-key quarter
  const int t = threadIdx.x;
  const int wv = t >> 6;
  const int m = wv >> 1;        // mixture
  const int u = wv & 1;         // 32-query tile within the 64
  const int lane = t & 63;
  const int quad = lane >> 4, l16 = lane & 15;
  const int perm = ((l16 >> 2) << 3) | (l16 & 3);
  const int bq = b * (NN * DK);
  const int bV = b * (DK * NN);

  // Q fragments: 2 subtiles x 2 chunks, f32 load + scale + pack in-register
  f16x8 qf[2][2];  // [su][chunk]
#pragma unroll
  for (int su = 0; su < 2; ++su)
#pragma unroll
    for (int c = 0; c < 2; ++c) {
      const float* qp_ = qt + bq + m * MIXOFF +
                         (qb * 64 + u * 32 + su * 16 + l16) * DM + quad * 8 + c * 32;
      f32x4 v0 = *(const f32x4*)qp_;
      f32x4 v1 = *(const f32x4*)(qp_ + 4);
      union { f16x8 v; f16x2 h[4]; } w;
      w.h[0] = pkrtz(v0[0] * QSCALE, v0[1] * QSCALE);
      w.h[1] = pkrtz(v0[2] * QSCALE, v0[3] * QSCALE);
      w.h[2] = pkrtz(v1[0] * QSCALE, v1[1] * QSCALE);
      w.h[3] = pkrtz(v1[2] * QSCALE, v1[3] * QSCALE);
      qf[su][c] = w.v;
    }

  // staging offsets (halfs): R12 unit maps, 256 units per K m-region / 512 V
  const int rK = t >> 3;                                            // key 0..31
  const int uuK = (t & 7) ^ ((rK & 3) ^ (((rK >> 3) & 1) << 2));    // R12 swizzle
  const int chV = t >> 2;                                           // ch 0..63
  const int uuV = (t & 3) ^ ((chV + (chV >> 2)) & 3);
  const int gKst = bq + kb * 32768 + rK * 64 + uuK * 8;
  const int gVst = bV + chV * NN + kb * 512 + uuV * 8;

  // LDS read offsets (halfs); R12 conflict-free maps
  const int gK = (l16 & 3) ^ (((l16 >> 2) & 1) << 2);
  const int hV = (l16 + (l16 >> 2)) & 3;
  const int kA = (quad ^ gK) * 8;
  const int kB = ((quad + 4) ^ gK) * 8;
  const int kbase = m * 2048 + perm * 64;
  const int vboff = 4096 + l16 * 32 + (quad ^ hV) * 8;

  const f32x4 z = {0.f, 0.f, 0.f, 0.f};
  f32x4 acc[2][8];  // [su][cc]
  float lsum[2] = {0.f, 0.f};
#pragma unroll
  for (int su = 0; su < 2; ++su)
#pragma unroll
    for (int cc = 0; cc < 8; ++cc) acc[su][cc] = z;

  STAGE(0, 0);
  int buf = 0;
  for (int s = 0; s < 16; ++s) {
    __syncthreads();  // tile for step s landed; reads of buf^1 done
    if (s + 1 < 16) STAGE(buf ^ 1, s + 1);
    const _Float16* sb_ = stg + buf * 8192;
    const _Float16* kp_ = sb_ + kbase;
    f16x8 kf0 = *(const f16x8*)(kp_ + kA);
    f16x8 kf1 = *(const f16x8*)(kp_ + kB);
    f16x8 kf2 = *(const f16x8*)(kp_ + 256 + kA);
    f16x8 kf3 = *(const f16x8*)(kp_ + 256 + kB);
    f16x8 pw[2];
#pragma unroll
    for (int su = 0; su < 2; ++su) {
      f32x4 s0 = MFMA32(kf1, qf[su][1], MFMA32(kf0, qf[su][0], z));
      f32x4 s1 = MFMA32(kf3, qf[su][1], MFMA32(kf2, qf[su][0], z));
      float e0 = EXP2(s0[0]), e1 = EXP2(s0[1]), e2 = EXP2(s0[2]), e3 = EXP2(s0[3]);
      float e4 = EXP2(s1[0]), e5 = EXP2(s1[1]), e6 = EXP2(s1[2]), e7 = EXP2(s1[3]);
      lsum[su] += ((e0 + e1) + (e2 + e3)) + ((e4 + e5) + (e6 + e7));
      union { f16x8 v; f16x2 h[4]; } w;
      w.h[0] = pkrtz(e0, e1); w.h[1] = pkrtz(e2, e3);
      w.h[2] = pkrtz(e4, e5); w.h[3] = pkrtz(e6, e7);
      pw[su] = w.v;
    }
    const _Float16* vb_ = sb_ + vboff;
    f16x8 vf[8];
#pragma unroll
    for (int cc = 0; cc < 8; ++cc) vf[cc] = *(const f16x8*)(vb_ + cc * 512);
#pragma unroll
    for (int cc = 0; cc < 8; ++cc)
#pragma unroll
      for (int su = 0; su < 2; ++su) acc[su][cc] = MFMA32(vf[cc], pw[su], acc[su][cc]);
    buf ^= 1;
  }

  // ---- epilogue: pure global stores of split-K partials (no LDS phases) ----
#pragma unroll
  for (int su = 0; su < 2; ++su) {
    lsum[su] += __shfl_xor(lsum[su], 16);
    lsum[su] += __shfl_xor(lsum[su], 32);
  }
  const size_t plane = (size_t)((b * 4 + kb) * 2 + m);
#pragma unroll
  for (int su = 0; su < 2; ++su) {
    const int qg = qb * 64 + u * 32 + su * 16 + l16;
    if (quad == 0) lpart[plane * 2048 + qg] = lsum[su];
    float* op = opart + (plane * 2048 + qg) * (size_t)128 + quad * 4;
#pragma unroll
    for (int cc = 0; cc < 8; ++cc) *(f32x4*)(op + cc * 16) = acc[su][cc];
  }
}

// ---- merge: prior softmax + split-K combine, FULLY COALESCED (R19) ----------
// R18's merge fetched 262MB for 64MB of opart (4x): 16B lane-pieces at 128B
// stride left 3/4 of every 64B sector unused, and the per-XCD revisit set
// (32 blk x 256 thr x 8 planes x 64B = 4MB) == L2 size -> thrash. Now each
// instruction reads one contiguous 4KB slab (thread t>>5 = q-row, (t&31)*16B
// in-row) so every sector is consumed whole, once. Per-q scale factors
// r[m][q] = prp[b*2+m]/sum_kb l precomputed in LDS.
__global__ __launch_bounds__(256) void merge_k(const float* __restrict__ qpart,
                                               const float* __restrict__ kern,
                                               const float* __restrict__ opart,
                                               const float* __restrict__ lpart,
                                               float* __restrict__ out) {
  __shared__ float barL[1024];
  __shared__ float lgp[16], exq[16], prp[16];
  __shared__ float r0q[64], r1q[64];
  const int t = threadIdx.x;
  const int b = blockIdx.x & 7;
  const int qc = blockIdx.x >> 3;  // 0..31, 64 q rows each
  const int qstart = qc * 64;
  for (int e = t; e < 1024; e += 256) {
    int bb = e >> 7, c = e & 127;
    float ss = 0.f;
#pragma unroll
    for (int seg = 0; seg < 8; ++seg) ss += qpart[(size_t)(bb * 8 + seg) * 128 + c];
    barL[e] = ss * (1.0f / 2048.0f);
  }
  __syncthreads();
  if (t < 16) {
    int mm = t >> 3, bb = t & 7;
    float ss = 0.f;
    for (int c = 0; c < DK; ++c) ss += kern[mm * DK + c] * barL[bb * 128 + c];
    lgp[t] = ss;
  }
  __syncthreads();
  if (t < 16) {
    int mm = t >> 3;
    float mx = lgp[mm * 8];
    for (int i2 = 1; i2 < 8; ++i2) mx = fmaxf(mx, lgp[mm * 8 + i2]);
    exq[t] = __expf(lgp[t] - mx);
  }
  __syncthreads();
  if (t < 16) {
    int mm = t >> 3;
    float sm = 0.f;
    for (int i2 = 0; i2 < 8; ++i2) sm += exq[mm * 8 + i2];
    prp[t] = exq[t] / sm;  // flat[m*8+b]; read as [b*2+m] (TF reshape quirk)
  }
  __syncthreads();
  if (t < 64) {
    const int q = qstart + t;
    float l0 = 0.f, l1 = 0.f;
#pragma unroll
    for (int kb = 0; kb < 4; ++kb) {
      l0 += lpart[((size_t)((b * 4 + kb) * 2 + 0)) * 2048 + q];
      l1 += lpart[((size_t)((b * 4 + kb) * 2 + 1)) * 2048 + q];
    }
    r0q[t] = prp[b * 2 + 0] / l0;
    r1q[t] = prp[b * 2 + 1] / l1;
  }
  __syncthreads();

  // j-slab loop: each instruction = 256 threads x 16B contiguous (4KB slab).
  const int qrow = t >> 5;           // 0..7 within slab
  const int doff = (t & 31) * 4;     // 0..124 floats
  const size_t pstride = (size_t)2048 * 128;
  const float* pb = opart + (size_t)(b * 8) * pstride + doff;
#pragma unroll
  for (int j = 0; j < 8; ++j) {
    const int ql = j * 8 + qrow;     // 0..63
    const float r0 = r0q[ql], r1 = r1q[ql];
    const size_t row = (size_t)(qstart + ql) * 128;
    f32x4 o = {0.f, 0.f, 0.f, 0.f};
#pragma unroll
    for (int kb = 0; kb < 4; ++kb) {
      f32x4 a0 = *(const f32x4*)(pb + (size_t)(kb * 2 + 0) * pstride + row);
      f32x4 a1 = *(const f32x4*)(pb + (size_t)(kb * 2 + 1) * pstride + row);
#pragma unroll
      for (int e = 0; e < 4; ++e) o[e] += a0[e] * r0 + a1[e] * r1;
    }
    *(f32x4*)(out + ((size_t)b * NN + qstart + ql) * DK + doff) = o;
  }
}

extern "C" void kernel_launch(void* const* d_in, const int* in_sizes, int n_in,
                              void* d_out, int out_size, void* d_ws, size_t ws_size,
                              hipStream_t stream) {
  const float* qt = (const float*)d_in[0];
  const float* kt = (const float*)d_in[1];
  const float* vt = (const float*)d_in[2];
  const float* kern = (const float*)d_in[3];
  float* out = (float*)d_out;

  char* ws = (char*)d_ws;
  float* qpart = (float*)(ws + 4096);          // 64*128 floats (32 KB)
  _Float16* khp = (_Float16*)(ws + 65536);     // 2M halfs (4 MB)
  _Float16* vTp = khp + (size_t)BS * NN * DK;  // 2M halfs (4 MB)
  float* opart = (float*)(ws + (32u << 20));   // [8b][4kb][2m][2048q][128d] f32 (64 MB)
  float* lpart = (float*)(ws + (96u << 20));   // [8b][4kb][2m][2048q] f32 (512 KB)

  prep_k<<<dim3(1088), dim3(256), 0, stream>>>(kt, khp, vt, vTp, qt, qpart);
  attn_k<<<dim3(1024), dim3(256), 0, stream>>>(qt, khp, vTp, opart, lpart);
  merge_k<<<dim3(256), dim3(256), 0, stream>>>(qpart, kern, opart, lpart, out);
}